// Round 1
// baseline (10774.998 us; speedup 1.0000x reference)
//
#include <hip/hip_runtime.h>

// HGCNConv: out = LeakyReLU_0.5( A @ (A^T @ embs) ), A sparse COO (vals, rows, cols)
// N=100000 nodes, H=50000 hyperedges, D=128, NNZ=3200000.
//
// Phase kernels: one edge per 32 lanes; lane q owns dims [4q, 4q+4) via float4.
// Gather side is coalesced (32 lanes read one contiguous 512B row).
// Scatter side uses unsafeAtomicAdd -> global_atomic_add_f32 (NOT a CAS loop).

#define HGCN_D 128
#define HGCN_H 50000

__global__ void hgcn_scatter_kernel(const float* __restrict__ vals,
                                    const float* __restrict__ src,   // [n_src, D]
                                    const int*   __restrict__ gidx,  // gather index per edge
                                    const int*   __restrict__ sidx,  // scatter index per edge
                                    float*       __restrict__ dst,   // [n_dst, D]
                                    int nnz) {
    long long t = (long long)blockIdx.x * blockDim.x + threadIdx.x;
    int e = (int)(t >> 5);      // edge id
    int q = (int)(t & 31);      // which float4 of the 128-dim row
    if (e >= nnz) return;

    float v = vals[e];
    int g = gidx[e];
    int s = sidx[e];

    const float4* src4 = (const float4*)(src + (long long)g * HGCN_D);
    float4 x = src4[q];

    float* dp = dst + (long long)s * HGCN_D + (q << 2);
    unsafeAtomicAdd(dp + 0, v * x.x);
    unsafeAtomicAdd(dp + 1, v * x.y);
    unsafeAtomicAdd(dp + 2, v * x.z);
    unsafeAtomicAdd(dp + 3, v * x.w);
}

__global__ void hgcn_leaky_kernel(float* __restrict__ out, int n4) {
    int i = blockIdx.x * blockDim.x + threadIdx.x;
    if (i >= n4) return;
    float4* p = (float4*)out;
    float4 x = p[i];
    x.x = x.x >= 0.f ? x.x : 0.5f * x.x;
    x.y = x.y >= 0.f ? x.y : 0.5f * x.y;
    x.z = x.z >= 0.f ? x.z : 0.5f * x.z;
    x.w = x.w >= 0.f ? x.w : 0.5f * x.w;
    p[i] = x;
}

extern "C" void kernel_launch(void* const* d_in, const int* in_sizes, int n_in,
                              void* d_out, int out_size, void* d_ws, size_t ws_size,
                              hipStream_t stream) {
    const float* vals = (const float*)d_in[0];
    const float* embs = (const float*)d_in[1];
    const int*   rows = (const int*)d_in[2];
    const int*   cols = (const int*)d_in[3];

    const int nnz     = in_sizes[0];
    const int n_nodes = in_sizes[1] / HGCN_D;

    float* out   = (float*)d_out;                 // [N, D]
    float* hyper = (float*)d_ws;                  // [H, D] scratch

    // zero accumulators (harness poisons d_out / d_ws with 0xAA)
    hipMemsetAsync(hyper, 0, (size_t)HGCN_H * HGCN_D * sizeof(float), stream);
    hipMemsetAsync(out,   0, (size_t)n_nodes * HGCN_D * sizeof(float), stream);

    const int block = 256;
    long long threads = (long long)nnz * 32;
    unsigned int grid = (unsigned int)((threads + block - 1) / block);

    // Phase 1: hyper[col] += val * embs[row]
    hgcn_scatter_kernel<<<grid, block, 0, stream>>>(vals, embs, rows, cols, hyper, nnz);
    // Phase 2: out[row] += val * hyper[col]
    hgcn_scatter_kernel<<<grid, block, 0, stream>>>(vals, hyper, cols, rows, out, nnz);
    // Phase 3: LeakyReLU(0.5)
    int n4 = (n_nodes * HGCN_D) / 4;
    hgcn_leaky_kernel<<<(n4 + block - 1) / block, block, 0, stream>>>(out, n4);
}

// Round 2
// 1514.447 us; speedup vs baseline: 7.1148x; 7.1148x over previous
//
#include <hip/hip_runtime.h>

// HGCNConv: out = LeakyReLU_0.5( A @ (A^T @ embs) ), A sparse COO.
// N=100000 nodes, H=50000 hyperedges, D=128, NNZ=3200000.
//
// Strategy: build CSR per phase on the fly (counting sort), then one wave per
// output row does a pure gather-reduce -> NO fp32 atomics (the baseline's
// 6.55 GB/dispatch atomic write-through was the bottleneck).

#define HGCN_D 128

// ---- counting-sort passes ------------------------------------------------

__global__ void hgcn_hist_kernel(const int* __restrict__ keys,
                                 int* __restrict__ cnt, int nnz) {
    int i = blockIdx.x * blockDim.x + threadIdx.x;
    if (i < nnz) atomicAdd(&cnt[keys[i]], 1);
}

// single-block exclusive scan: reads cnt[0..n), writes offs[0..n] and cur[0..n)
// (cnt and cur may alias: each element is read once before being rewritten by
// the same thread; the scan itself runs in LDS)
__global__ void hgcn_scan_kernel(const int* __restrict__ cnt,
                                 int* __restrict__ offs,
                                 int* __restrict__ cur, int n) {
    __shared__ int buf[1024];
    __shared__ int carry_s;
    int tid = threadIdx.x;
    if (tid == 0) carry_s = 0;
    __syncthreads();
    for (int base = 0; base < n; base += 1024) {
        int i = base + tid;
        int x = (i < n) ? cnt[i] : 0;
        buf[tid] = x;
        __syncthreads();
        // Hillis-Steele inclusive scan over 1024
        for (int off = 1; off < 1024; off <<= 1) {
            int y = (tid >= off) ? buf[tid - off] : 0;
            __syncthreads();
            buf[tid] += y;
            __syncthreads();
        }
        int incl = buf[tid];
        int excl = incl - x;
        int carry = carry_s;
        if (i < n) { offs[i] = carry + excl; cur[i] = carry + excl; }
        __syncthreads();                  // everyone read carry_s
        if (tid == 1023) carry_s = carry + incl;
        __syncthreads();
    }
    if (tid == 0) offs[n] = carry_s;
}

// ticketed scatter: perm[pos] = (val_bits, other_idx), pos = cur[key]++
__global__ void hgcn_scatter_kernel(const float* __restrict__ vals,
                                    const int* __restrict__ keys,
                                    const int* __restrict__ other,
                                    int* __restrict__ cur,
                                    int2* __restrict__ perm, int nnz) {
    int i = blockIdx.x * blockDim.x + threadIdx.x;
    if (i < nnz) {
        int p = atomicAdd(&cur[keys[i]], 1);
        perm[p] = make_int2(__float_as_int(vals[i]), other[i]);
    }
}

// ---- gather-reduce: one 64-lane wave per output row ----------------------
// lane owns dims [2*lane, 2*lane+1]; edge (val, src_idx) pairs are loaded
// cooperatively (64 at a time, coalesced) and broadcast via __shfl.

__global__ void hgcn_gather_kernel(const int2* __restrict__ perm,
                                   const int* __restrict__ offs,
                                   const float* __restrict__ src,
                                   float* __restrict__ dst,
                                   int n_dst, int do_relu) {
    int wid  = (int)(((long long)blockIdx.x * blockDim.x + threadIdx.x) >> 6);
    int lane = threadIdx.x & 63;
    if (wid >= n_dst) return;

    int s = offs[wid];
    int e = offs[wid + 1];
    float2 acc = make_float2(0.f, 0.f);

    for (int base = s; base < e; base += 64) {
        int n = e - base;
        if (n > 64) n = 64;
        int2 p = make_int2(0, 0);
        if (lane < n) p = perm[base + lane];
        float pv = __int_as_float(p.x);

        if (n == 64) {
            #pragma unroll 8
            for (int j = 0; j < 64; ++j) {
                float vj = __shfl(pv, j);
                int   ij = __shfl(p.y, j);
                float2 x = ((const float2*)(src + (long long)ij * HGCN_D))[lane];
                acc.x += vj * x.x;
                acc.y += vj * x.y;
            }
        } else {
            for (int j = 0; j < n; ++j) {
                float vj = __shfl(pv, j);
                int   ij = __shfl(p.y, j);
                float2 x = ((const float2*)(src + (long long)ij * HGCN_D))[lane];
                acc.x += vj * x.x;
                acc.y += vj * x.y;
            }
        }
    }

    if (do_relu) {
        acc.x = acc.x >= 0.f ? acc.x : 0.5f * acc.x;
        acc.y = acc.y >= 0.f ? acc.y : 0.5f * acc.y;
    }
    ((float2*)(dst + (long long)wid * HGCN_D))[lane] = acc;
}

extern "C" void kernel_launch(void* const* d_in, const int* in_sizes, int n_in,
                              void* d_out, int out_size, void* d_ws, size_t ws_size,
                              hipStream_t stream) {
    const float* vals = (const float*)d_in[0];
    const float* embs = (const float*)d_in[1];
    const int*   rows = (const int*)d_in[2];
    const int*   cols = (const int*)d_in[3];

    const int nnz     = in_sizes[0];
    const int n_nodes = in_sizes[1] / HGCN_D;   // N = 100000
    const int n_hyper = out_size ? (int)(((const int*)in_sizes)[0], 0) : 0; // unused
    // n_hyperedges from scalar input (in dict order: index 5), but sizes are 1;
    // derive H from max practical: it's a python scalar passed as input 5.
    const int H = ((const int*)d_in[5]) ? 0 : 0; // can't read device scalar here
    (void)n_hyper; (void)H;
    const int n_hyperedges = 50000;             // fixed by problem spec

    float* out = (float*)d_out;                 // [N, D]

    // workspace layout (all 256B-aligned)
    char* ws = (char*)d_ws;
    float* hyper = (float*)ws;                                   // H*D floats
    size_t off = (size_t)n_hyperedges * HGCN_D * sizeof(float);
    off = (off + 255) & ~(size_t)255;
    int2* perm = (int2*)(ws + off);                              // nnz pairs
    off += (size_t)nnz * sizeof(int2);
    off = (off + 255) & ~(size_t)255;
    int* offs = (int*)(ws + off);                                // (N+1) ints
    off += (size_t)(n_nodes + 1) * sizeof(int);
    off = (off + 255) & ~(size_t)255;
    int* cur = (int*)(ws + off);                                 // N ints

    const int block = 256;
    int egrid = (nnz + block - 1) / block;

    // ---- phase 1: hyper[c] = sum val * embs[r]  (group by cols) ----
    hipMemsetAsync(cur, 0, (size_t)n_hyperedges * sizeof(int), stream);
    hgcn_hist_kernel<<<egrid, block, 0, stream>>>(cols, cur, nnz);
    hgcn_scan_kernel<<<1, 1024, 0, stream>>>(cur, offs, cur, n_hyperedges);
    hgcn_scatter_kernel<<<egrid, block, 0, stream>>>(vals, cols, rows, cur, perm, nnz);
    {
        int waves_blocks = (n_hyperedges * 64 + block - 1) / block;
        hgcn_gather_kernel<<<waves_blocks, block, 0, stream>>>(perm, offs, embs,
                                                               hyper, n_hyperedges, 0);
    }

    // ---- phase 2: out[r] = LeakyReLU( sum val * hyper[c] )  (group by rows) ----
    hipMemsetAsync(cur, 0, (size_t)n_nodes * sizeof(int), stream);
    hgcn_hist_kernel<<<egrid, block, 0, stream>>>(rows, cur, nnz);
    hgcn_scan_kernel<<<1, 1024, 0, stream>>>(cur, offs, cur, n_nodes);
    hgcn_scatter_kernel<<<egrid, block, 0, stream>>>(vals, rows, cols, cur, perm, nnz);
    {
        int waves_blocks = (n_nodes * 64 + block - 1) / block;
        hgcn_gather_kernel<<<waves_blocks, block, 0, stream>>>(perm, offs, hyper,
                                                               out, n_nodes, 1);
    }
}